// Round 3
// baseline (375.559 us; speedup 1.0000x reference)
//
#include <hip/hip_runtime.h>
#include <hip/hip_bf16.h>
#include <stdint.h>

#define NR 384          // total rows
#define DD 73728        // C*H*W
#define KSPLIT 128      // split-K factor (768 blocks = 3/CU, fully resident)
#define KCH 576         // DD / KSPLIT
#define BK 32           // K-tile per iteration
#define NIT 18          // KCH / BK
#define RS 40           // LDS row stride bf16 (80 B, 2-way max on b128 reads)
#define TILE_F 16384    // 128*128 floats per tile
#define KSTRIDE (9 * TILE_F)   // floats per ks in Gp9
#define NBLK (6 * KSPLIT)      // 768

typedef __bf16 bf16;
typedef __attribute__((ext_vector_type(4))) __bf16 bf16x4;
typedef __attribute__((ext_vector_type(8))) __bf16 bf16x8;
typedef __attribute__((ext_vector_type(4))) float f32x4;

// T4 barrier: publish LDS (lgkmcnt(0)) but do NOT drain vmcnt -- prefetched
// global loads for tile it+2 stay in flight across the barrier. hipcc's
// __syncthreads() emits s_waitcnt vmcnt(0) and killed the prefetch 18x/block.
__device__ __forceinline__ void bar_lgkm() {
    asm volatile("s_waitcnt lgkmcnt(0)" ::: "memory");
    __builtin_amdgcn_s_barrier();
    asm volatile("" ::: "memory");
}

__global__ __launch_bounds__(256, 3) void k_all(const float* __restrict__ X,
                                                const float* __restrict__ M,
                                                float* __restrict__ Gp9,
                                                float* __restrict__ Dp,
                                                float* __restrict__ rt,
                                                unsigned* __restrict__ ctr,
                                                float* __restrict__ out) {
    __shared__ __align__(16) char sbuf[41984];     // 41 KB -> 3 blocks/CU
    bf16* ash = (bf16*)sbuf;                       // [2][128*RS] = 20 KB
    bf16* bsh = (bf16*)(sbuf + 20480);             // [2][128*RS] = 20 KB

    const int tid  = threadIdx.x;
    const int lane = tid & 63;
    const int w    = tid >> 6;
    const int quad = lane >> 4;
    const int l15  = lane & 15;
    const int wm   = w & 1, wn = w >> 1;
    const int srow = tid >> 3;           // staging row base 0..31
    const int fseg = tid & 7;            // 16B segment within 128B row-chunk
    const int mds  = (srow >> 2) & 3;    // dataset id (same for all p)

    int xcd  = blockIdx.x & 7;
    int g    = blockIdx.x >> 3;
    int tile = g % 6;
    int ks   = xcd + 8 * (g / 6);        // 6 tiles of one ks share an XCD
    int tm = (tile < 3) ? 0 : ((tile < 5) ? 1 : 2);
    int tn = (tile < 3) ? tile : ((tile < 5) ? (tile - 2) : 2);
    const bool diag = (tm == tn);
    const float* Xa = X + (size_t)(tm * 128) * DD;
    const float* Xb = X + (size_t)(tn * 128) * DD;
    const float* Mr = M + (size_t)mds * DD;   // M slice: 9.2 KB/ks, L2-hot
    size_t k0 = (size_t)ks * KCH;

    f32x4 acc[4][4];
#pragma unroll
    for (int i = 0; i < 4; ++i)
#pragma unroll
        for (int j = 0; j < 4; ++j) acc[i][j] = (f32x4){0.f, 0.f, 0.f, 0.f};

    float4 xa[4], xb[4], m4;             // single register buffer
    auto load_regs = [&](int it) {
        size_t gk = k0 + (size_t)it * BK + fseg * 4;
        m4 = *(const float4*)(Mr + gk);  // replaces msh LDS read (bit-identical)
#pragma unroll
        for (int p = 0; p < 4; ++p) {
            int row = p * 32 + srow;
            xa[p] = *(const float4*)(Xa + (size_t)row * DD + gk);
            if (!diag) xb[p] = *(const float4*)(Xb + (size_t)row * DD + gk);
        }
    };
    auto write_tiles = [&](int it, int buf) {
#pragma unroll
        for (int p = 0; p < 4; ++p) {
            int row = p * 32 + srow;
            bf16x4 za;
            za[0] = (bf16)(xa[p].x - m4.x); za[1] = (bf16)(xa[p].y - m4.y);
            za[2] = (bf16)(xa[p].z - m4.z); za[3] = (bf16)(xa[p].w - m4.w);
            *(bf16x4*)&ash[buf * 5120 + row * RS + fseg * 4] = za;
            if (!diag) {
                bf16x4 zb;
                zb[0] = (bf16)(xb[p].x - m4.x); zb[1] = (bf16)(xb[p].y - m4.y);
                zb[2] = (bf16)(xb[p].z - m4.z); zb[3] = (bf16)(xb[p].w - m4.w);
                *(bf16x4*)&bsh[buf * 5120 + row * RS + fseg * 4] = zb;
            }
        }
    };
    auto compute = [&](int buf) {
        const bf16* bb = diag ? (ash + buf * 5120) : (bsh + buf * 5120);
        bf16x8 af[4], bfv[4];
#pragma unroll
        for (int i = 0; i < 4; ++i) {
            int r = wm * 64 + i * 16 + l15;
            af[i] = *(const bf16x8*)&ash[buf * 5120 + r * RS + quad * 8];
        }
#pragma unroll
        for (int j = 0; j < 4; ++j) {
            int r = wn * 64 + j * 16 + l15;
            bfv[j] = *(const bf16x8*)&bb[r * RS + quad * 8];
        }
#pragma unroll
        for (int i = 0; i < 4; ++i)
#pragma unroll
            for (int j = 0; j < 4; ++j)
                acc[i][j] = __builtin_amdgcn_mfma_f32_16x16x32_bf16(
                    af[i], bfv[j], acc[i][j], 0, 0, 0);
    };

    load_regs(0);
    write_tiles(0, 0);            // compiler waits vmcnt for load(0) regs only
    load_regs(1);
    bar_lgkm();                   // publish L[0]; loads for it=1 stay in flight

    for (int it = 0; it < NIT; ++it) {
        int buf = it & 1;
        if (it + 1 < NIT) {
            write_tiles(it + 1, buf ^ 1);    // overlaps compute below
            if (it + 2 < NIT) load_regs(it + 2);
        }
        compute(buf);
        bar_lgkm();               // publishes L[buf^1]; prefetch NOT drained
    }

    // ---- epilogue 1: normal-orientation tile (coalesced, from regs)
    float* gp = Gp9 + (size_t)ks * KSTRIDE + (size_t)(tm * 3 + tn) * TILE_F;
#pragma unroll
    for (int i = 0; i < 4; ++i) {
        int lr0 = wm * 64 + i * 16 + quad * 4;
#pragma unroll
        for (int j = 0; j < 4; ++j) {
            int lc = wn * 64 + j * 16 + l15;
#pragma unroll
            for (int r = 0; r < 4; ++r)
                gp[(lr0 + r) * 128 + lc] = acc[i][j][r];
        }
    }

    // ---- epilogue 2: diag blocks emit norm^2 partials (row == col elems)
    if (diag) {
        if (wm == wn && (l15 >> 2) == quad) {
#pragma unroll
            for (int i = 0; i < 4; ++i)
                Dp[(size_t)ks * NR + tm * 128 + wm * 64 + i * 16 + l15] =
                    acc[i][i][l15 & 3];
        }
    } else {
        // ---- epilogue 3: transposed copy via padded LDS (sbuf free now)
        float* tb = (float*)sbuf;                 // 64 x 129 floats = 33 KB
        float* gpT = Gp9 + (size_t)ks * KSTRIDE + (size_t)(tn * 3 + tm) * TILE_F;
#pragma unroll
        for (int h = 0; h < 2; ++h) {
            bar_lgkm();                           // tb free / prev half read
            if (wm == h) {
#pragma unroll
                for (int i = 0; i < 4; ++i) {
                    int rr0 = i * 16 + quad * 4;  // row within half 0..63
#pragma unroll
                    for (int j = 0; j < 4; ++j) {
                        int cc = wn * 64 + j * 16 + l15;
#pragma unroll
                        for (int r = 0; r < 4; ++r)
                            tb[(rr0 + r) * 129 + cc] = acc[i][j][r];
                    }
                }
            }
            bar_lgkm();
#pragma unroll
            for (int rep = 0; rep < 32; ++rep) {
                int idx = rep * 256 + tid;        // 8192 = 128 cols x 64 rows
                int c = idx >> 6;
                int r = idx & 63;
                gpT[c * 128 + h * 64 + r] = tb[r * 129 + c];
            }
        }
    }

    // ---- grid barrier: gram done -> tail (blocks 0..383 only)
    __syncthreads();              // per-wave vmcnt(0): all global stores done
    if (tid == 0) {
        __threadfence();          // L2 writeback to device coherence point
        __hip_atomic_fetch_add(ctr, 1u, __ATOMIC_RELEASE,
                               __HIP_MEMORY_SCOPE_AGENT);
    }
    if (blockIdx.x >= NR) return; // 384 blocks exit, freeing CU slots

    if (tid == 0) {
        while (__hip_atomic_load(ctr, __ATOMIC_ACQUIRE,
                                 __HIP_MEMORY_SCOPE_AGENT) < (unsigned)NBLK)
            __builtin_amdgcn_s_sleep(2);
        __threadfence();          // invalidate stale L1/L2 before remote reads
    }
    __syncthreads();

    // ---- tail: block a == blockIdx.x, 256 threads cover 384 columns
    float* invn_sh = (float*)sbuf;            // [384]
    float* sv      = (float*)(sbuf + 1536);   // [384]
    float* wred    = (float*)(sbuf + 3072);   // [4]
    int*   lastf   = (int*)(sbuf + 3088);

    const int a  = blockIdx.x;
    const int pa = a >> 7;

    for (int b = tid; b < NR; b += 256) {     // inverse norms (ks ascending)
        float s2 = 0.f;
        const float* dp = Dp + b;
#pragma unroll 8
        for (int kk = 0; kk < KSPLIT; ++kk) s2 += dp[(size_t)kk * NR];
        invn_sh[b] = 1.f / fmaxf(sqrtf(s2), 1e-6f);
    }
    __syncthreads();

    const float ia = invn_sh[a];
    float eacc = 0.f;
    for (int b = tid; b < NR; b += 256) {     // row a of G (ks ascending)
        const int pb = b >> 7;
        const float* gbase = Gp9 + (size_t)(pa * 3 + pb) * TILE_F
                           + (size_t)(a & 127) * 128 + (b & 127);
        float gsum = 0.f;
#pragma unroll 8
        for (int kk = 0; kk < KSPLIT; ++kk) gsum += gbase[(size_t)kk * KSTRIDE];
        float s = gsum * ia * invn_sh[b] * 10.0f;
        sv[b] = s;
        if ((b & 15) != (a & 15)) eacc += expf(s);
    }
#pragma unroll
    for (int o = 32; o > 0; o >>= 1) eacc += __shfl_down(eacc, o);
    if (lane == 0) wred[w] = eacc;
    __syncthreads();

    if (tid == 0) {
        float Dsa = wred[0] + wred[1] + wred[2] + wred[3];
        int pr[4];
        if (a < 16)       { pr[0] = 192 + a; pr[1] = a + 16;  pr[2] = a + 192; pr[3] = a + 368; }
        else if (a < 192) { pr[0] = 192 + a; pr[1] = a + 16;  pr[2] = a + 192; pr[3] = a - 16; }
        else if (a < 368) { pr[0] = a - 192; pr[1] = a + 16;  pr[2] = a - 192; pr[3] = a - 16; }
        else              { pr[0] = a - 192; pr[1] = a - 368; pr[2] = a - 192; pr[3] = a - 16; }
        float t = 0.f;
#pragma unroll
        for (int sidx = 0; sidx < 4; ++sidx) {
            float num = sv[pr[sidx]];
            t += -num + logf(expf(num) + Dsa);
        }
        rt[a] = t;
        __threadfence();
        unsigned prev = __hip_atomic_fetch_add(ctr + 1, 1u, __ATOMIC_ACQ_REL,
                                               __HIP_MEMORY_SCOPE_AGENT);
        *lastf = (prev == (unsigned)(NR - 1));
    }
    __syncthreads();

    if (*lastf) {                 // last tail block reduces 384 terms -> out
        __threadfence();
        float v = rt[tid] + ((tid < NR - 256) ? rt[256 + tid] : 0.0f);
#pragma unroll
        for (int o = 32; o > 0; o >>= 1) v += __shfl_down(v, o);
        if (lane == 0) wred[w] = v;
        __syncthreads();
        if (tid == 0)
            out[0] = (wred[0] + wred[1] + wred[2] + wred[3]) * (1.0f / 576.0f);
    }
}

// ---------------------------------------------------------------- launch
extern "C" void kernel_launch(void* const* d_in, const int* in_sizes, int n_in,
                              void* d_out, int out_size, void* d_ws, size_t ws_size,
                              hipStream_t stream) {
    const float* X = (const float*)d_in[0];
    const float* M = (const float*)d_in[1];
    float* out = (float*)d_out;

    char* ws = (char*)d_ws;
    float* Gp9 = (float*)ws;                                   // 75.5 MB
    float* Dp  = Gp9 + (size_t)KSPLIT * KSTRIDE;               // 196.6 KB
    float* rt  = Dp + (size_t)KSPLIT * NR;                     // 1.5 KB
    unsigned* ctr = (unsigned*)(rt + NR);                      // [0]=gram,[1]=tail

    hipMemsetAsync(ctr, 0, 2 * sizeof(unsigned), stream);
    k_all<<<dim3(NBLK), dim3(256), 0, stream>>>(X, M, Gp9, Dp, rt, ctr, out);
}

// Round 4
// 191.780 us; speedup vs baseline: 1.9583x; 1.9583x over previous
//
#include <hip/hip_runtime.h>
#include <hip/hip_bf16.h>
#include <stdint.h>

#define NR 384          // total rows
#define DD 73728        // C*H*W
#define PDV 16          // N_PARTS * N_DATASETS
#define BSV 192         // batch size
#define KSPLIT 128      // split-K factor (768 blocks = 3/CU, fully resident)
#define KCH 576         // DD / KSPLIT
#define BK 32           // K-tile per iteration
#define NIT 18          // KCH / BK
#define RS 40           // LDS row stride bf16 (80 B = 20 banks, 16B-aligned)

typedef __bf16 bf16;
typedef __attribute__((ext_vector_type(4))) __bf16 bf16x4;
typedef __attribute__((ext_vector_type(8))) __bf16 bf16x8;
typedef __attribute__((ext_vector_type(4))) float f32x4;

// ---------------------------------------------------------------- kernel 1
// Fused demean + cast + partial Gram. (R0-verified: 1 barrier/iter LDS
// double-buffer; ds_write(tile it+1) and ds_read+MFMA(tile it) co-schedule
// between the same barriers. R3 counters showed this phase is latency-bound
// (not BW: FETCH 95 MB < X's 113 MB) -- structural changes to it regressed
// every time; kept verbatim.)
__global__ __launch_bounds__(256, 3) void k_gram(const float* __restrict__ X,
                                                 const float* __restrict__ M,
                                                 float* __restrict__ Gp) {
    __shared__ float msh[4 * KCH];       // 9.2 KB
    __shared__ bf16 ash[2][128 * RS];    // 20 KB
    __shared__ bf16 bsh[2][128 * RS];    // 20 KB  (total 49.2 KB, 3/CU OK)
    const int tid  = threadIdx.x;
    const int lane = tid & 63;
    const int w    = tid >> 6;
    const int quad = lane >> 4;
    const int l15  = lane & 15;
    const int wm   = w & 1, wn = w >> 1;
    const int srow = tid >> 3;           // staging row base 0..31
    const int fseg = tid & 7;            // 16B segment within 128B row-chunk
    const int mds  = (srow >> 2) & 3;    // dataset id (same for all p)

    int xcd  = blockIdx.x & 7;
    int g    = blockIdx.x >> 3;
    int tile = g % 6;
    int ks   = xcd + 8 * (g / 6);        // 6 tiles of one ks share an XCD
    int tm = (tile < 3) ? 0 : ((tile < 5) ? 1 : 2);
    int tn = (tile < 3) ? tile : ((tile < 5) ? (tile - 2) : 2);
    const bool diag = (tm == tn);
    const float* Xa = X + (size_t)(tm * 128) * DD;
    const float* Xb = X + (size_t)(tn * 128) * DD;
    size_t k0 = (size_t)ks * KCH;

    // ---- stage M slice once: 4 datasets x 576 floats
    for (int i = tid; i < 4 * 144; i += 256) {
        int ds = i / 144;
        int c  = (i - ds * 144) * 4;
        *(float4*)&msh[ds * KCH + c] = *(const float4*)(M + (size_t)ds * DD + k0 + c);
    }

    f32x4 acc[4][4];
#pragma unroll
    for (int i = 0; i < 4; ++i)
#pragma unroll
        for (int j = 0; j < 4; ++j) acc[i][j] = (f32x4){0.f, 0.f, 0.f, 0.f};

    float4 xa[4], xb[4];                 // single register buffer
    auto load_regs = [&](int it) {
        size_t gk = k0 + (size_t)it * BK + fseg * 4;
#pragma unroll
        for (int p = 0; p < 4; ++p) {
            int row = p * 32 + srow;
            xa[p] = *(const float4*)(Xa + (size_t)row * DD + gk);
            if (!diag) xb[p] = *(const float4*)(Xb + (size_t)row * DD + gk);
        }
    };
    auto write_tiles = [&](int it, int buf) {
        int kc = it * BK + fseg * 4;
        float4 m4 = *(const float4*)&msh[mds * KCH + kc];   // ONE read, all p
#pragma unroll
        for (int p = 0; p < 4; ++p) {
            int row = p * 32 + srow;
            bf16x4 za;
            za[0] = (bf16)(xa[p].x - m4.x); za[1] = (bf16)(xa[p].y - m4.y);
            za[2] = (bf16)(xa[p].z - m4.z); za[3] = (bf16)(xa[p].w - m4.w);
            *(bf16x4*)&ash[buf][row * RS + fseg * 4] = za;
            if (!diag) {
                bf16x4 zb;
                zb[0] = (bf16)(xb[p].x - m4.x); zb[1] = (bf16)(xb[p].y - m4.y);
                zb[2] = (bf16)(xb[p].z - m4.z); zb[3] = (bf16)(xb[p].w - m4.w);
                *(bf16x4*)&bsh[buf][row * RS + fseg * 4] = zb;
            }
        }
    };
    auto compute = [&](int buf) {
        const bf16* bb = diag ? ash[buf] : bsh[buf];
        bf16x8 af[4], bfv[4];
#pragma unroll
        for (int i = 0; i < 4; ++i) {
            int r = wm * 64 + i * 16 + l15;
            af[i] = *(const bf16x8*)&ash[buf][r * RS + quad * 8];
        }
#pragma unroll
        for (int j = 0; j < 4; ++j) {
            int r = wn * 64 + j * 16 + l15;
            bfv[j] = *(const bf16x8*)&bb[r * RS + quad * 8];
        }
#pragma unroll
        for (int i = 0; i < 4; ++i)
#pragma unroll
            for (int j = 0; j < 4; ++j)
                acc[i][j] = __builtin_amdgcn_mfma_f32_16x16x32_bf16(
                    af[i], bfv[j], acc[i][j], 0, 0, 0);
    };

    load_regs(0);
    __syncthreads();              // msh visible
    write_tiles(0, 0);            // vmcnt drains load(0) only
    load_regs(1);
    __syncthreads();              // L[0] published

    for (int it = 0; it < NIT; ++it) {
        int buf = it & 1;
        if (it + 1 < NIT) {
            write_tiles(it + 1, buf ^ 1);    // overlaps compute below
            if (it + 2 < NIT) load_regs(it + 2);
        }
        compute(buf);
        __syncthreads();          // publishes L[buf^1]; frees L[buf]
    }

    float* gp = Gp + ((size_t)(ks * 6 + tile) << 14);
#pragma unroll
    for (int i = 0; i < 4; ++i) {
        int lr0 = wm * 64 + i * 16 + quad * 4;
#pragma unroll
        for (int j = 0; j < 4; ++j) {
            int lc = wn * 64 + j * 16 + l15;
#pragma unroll
            for (int r = 0; r < 4; ++r)
                gp[(lr0 + r) * 128 + lc] = acc[i][j][r];
        }
    }
}

// ---------------------------------------------------------------- kernel 2
// Reduce partials -> full symmetric G + per-row inverse norm. Zeroes out[0].
__global__ __launch_bounds__(256) void k_red(const float* __restrict__ Gp,
                                             float* __restrict__ G,
                                             float* __restrict__ invn,
                                             float* __restrict__ out) {
    int t    = blockIdx.x * 256 + threadIdx.x;
    if (t == 0) out[0] = 0.0f;
    int tile = t >> 14;
    int idx  = t & 16383;
    int lr   = idx >> 7, lc = idx & 127;
    const float* p = Gp + ((size_t)tile << 14) + idx;
    float s = 0.0f;
#pragma unroll 8
    for (int ks = 0; ks < KSPLIT; ++ks) s += p[(size_t)ks * 98304];
    int tm = (tile < 3) ? 0 : ((tile < 5) ? 1 : 2);
    int tn = (tile < 3) ? tile : ((tile < 5) ? (tile - 2) : 2);
    int a = tm * 128 + lr, b = tn * 128 + lc;
    G[(size_t)a * NR + b] = s;
    G[(size_t)b * NR + a] = s;
    if (a == b) invn[a] = 1.0f / fmaxf(sqrtf(s), 1e-6f);
}

// ---------------------------------------------------------------- kernel 3
// One wave per row a. R4 change vs R0: (1) the 4 waves of a block reduce
// their row terms in LDS and issue ONE atomicAdd per block -- 96 device-
// scope same-address RMWs instead of 384 (each is a serialized trip through
// the cross-XCD coherence point, ~100-200 cyc); (2) each wave caches its
// row's s-values in LDS so lane 0's 4 pair-slot numerators come from LDS
// instead of 4 dependent ~400-cyc global loads (bit-identical values: same
// inputs, same ops).
__global__ __launch_bounds__(256) void k_dsum(const float* __restrict__ G,
                                              const float* __restrict__ invn,
                                              float* __restrict__ out) {
    __shared__ float sv[4][NR];          // 6 KB: per-wave row s-values
    __shared__ float tsh[4];
    const int lane = threadIdx.x & 63;
    const int w    = threadIdx.x >> 6;
    const int a    = blockIdx.x * 4 + w;
    float ia  = invn[a];
    int arem  = a & 15;
    float acc = 0.0f;
    for (int b = lane; b < NR; b += 64) {
        float s = G[(size_t)a * NR + b] * ia * invn[b] * 10.0f;
        sv[w][b] = s;
        if ((b & 15) != arem) acc += expf(s);
    }
#pragma unroll
    for (int o = 32; o > 0; o >>= 1) acc += __shfl_down(acc, o);
    if (lane == 0) {
        float Dsa = acc;
        int pr[4];
        if (a < 16)       { pr[0] = 192 + a; pr[1] = a + 16;  pr[2] = a + 192; pr[3] = a + 368; }
        else if (a < 192) { pr[0] = 192 + a; pr[1] = a + 16;  pr[2] = a + 192; pr[3] = a - 16; }
        else if (a < 368) { pr[0] = a - 192; pr[1] = a + 16;  pr[2] = a - 192; pr[3] = a - 16; }
        else              { pr[0] = a - 192; pr[1] = a - 368; pr[2] = a - 192; pr[3] = a - 16; }
        float t = 0.0f;
#pragma unroll
        for (int s = 0; s < 4; ++s) {
            float num = sv[w][pr[s]];    // same value as reloading G (ops identical)
            t += -num + logf(expf(num) + Dsa);
        }
        tsh[w] = t;
    }
    __syncthreads();
    if (threadIdx.x == 0)
        atomicAdd(out, (tsh[0] + tsh[1] + tsh[2] + tsh[3]) * (1.0f / 576.0f));
}

// ---------------------------------------------------------------- launch
extern "C" void kernel_launch(void* const* d_in, const int* in_sizes, int n_in,
                              void* d_out, int out_size, void* d_ws, size_t ws_size,
                              hipStream_t stream) {
    const float* X = (const float*)d_in[0];
    const float* M = (const float*)d_in[1];
    float* out = (float*)d_out;

    char* ws = (char*)d_ws;
    float* Gp   = (float*)ws;                                  // 50.3 MB
    float* G    = Gp + (size_t)KSPLIT * 6 * 16384;             // 590 KB
    float* invn = G + (size_t)NR * NR;

    k_gram<<<dim3(6 * KSPLIT), dim3(256), 0, stream>>>(X, M, Gp);
    k_red<<<dim3(384), dim3(256), 0, stream>>>(Gp, G, invn, out);
    k_dsum<<<dim3(NR / 4), dim3(256), 0, stream>>>(G, invn, out);
}